// Round 5
// baseline (3491.507 us; speedup 1.0000x reference)
//
#include <hip/hip_runtime.h>
#include <cstdint>
#include <cstddef>

typedef _Float16 f16;
typedef _Float16 f16x2 __attribute__((ext_vector_type(2)));
typedef _Float16 f16x8 __attribute__((ext_vector_type(8)));
typedef float f32x4 __attribute__((ext_vector_type(4)));

#define NB_TOT   2048
#define F0_      39
#define DDIM     32
#define HROW     104            // padded hidden row (f16), 208B, 16B-aligned rows
#define HBATCH   (DDIM*HROW)    // 3328 f16 per batch
// slab: [step][mt(13)][lane(64)][j(8)] f16  -> per-step 6656 f16 = 13312 B
#define SLAB_F16S 6656
#define SLAB_BYTES 13312

// workspace layout (bytes)
#define SZ_H     ((size_t)NB_TOT*HBATCH*2)
#define OFF_H0   ((size_t)0)
#define OFF_H1   (OFF_H0 + SZ_H)
#define OFF_H2   (OFF_H1 + SZ_H)
#define OFF_W0   (OFF_H2 + SZ_H)
#define SZ_W0    ((size_t)50*SLAB_BYTES)
#define OFF_W1   (OFF_W0 + SZ_W0)
#define SZ_W12   ((size_t)130*SLAB_BYTES)
#define OFF_W2   (OFF_W1 + SZ_W12)
#define OFF_BIAS (OFF_W2 + SZ_W12)

// ---------------- prep kernels ----------------

// h0[b][d][n] = (n<39) ? x[b][n][d] : 0   (fp16, transposed, zero-padded)
__global__ void k_prep_h0(const float* __restrict__ x, f16* __restrict__ h0) {
    long idx = (long)blockIdx.x * 256 + threadIdx.x;
    if (idx >= (long)NB_TOT * HBATCH) return;
    int n = (int)(idx % HROW);
    long t = idx / HROW;
    int d = (int)(t % DDIM);
    long b = t / DDIM;
    float v = 0.f;
    if (n < F0_) v = x[(b * F0_ + n) * DDIM + d];
    h0[idx] = (f16)v;
}

// slab[step][mt][lane][j] = W[m*hn+n][o]
//   lane = quad*16+d0; o = mt*16+d0; m = (step%10)*4+quad; n = (step/10)*8+j
// zeros where o>=200 | m>=39 | n>=hn
__global__ void k_prep_w(const float* __restrict__ W, f16* __restrict__ slab,
                         int nsteps, int hn) {
    long idx = (long)blockIdx.x * 256 + threadIdx.x;
    if (idx >= (long)nsteps * SLAB_F16S) return;
    int j = (int)(idx & 7);
    long t = idx >> 3;
    int lane = (int)(t & 63); t >>= 6;
    int mt = (int)(t % 13);
    int step = (int)(t / 13);
    int quad = lane >> 4, d0 = lane & 15;
    int o = mt * 16 + d0;
    int m = (step % 10) * 4 + quad;
    int n = (step / 10) * 8 + j;
    float v = 0.f;
    if (o < 200 && m < F0_ && n < hn)
        v = W[((long)m * hn + n) * 200 + o];
    slab[idx] = (f16)v;
}

__global__ void k_prep_bias(const float* __restrict__ b0, const float* __restrict__ b1,
                            const float* __restrict__ b2, float* __restrict__ dst) {
    int idx = blockIdx.x * 256 + threadIdx.x;
    if (idx >= 3 * 208) return;
    int L = idx / 208, o = idx % 208;
    const float* s = (L == 0) ? b0 : (L == 1 ? b1 : b2);
    dst[idx] = (o < 200) ? s[o] : 0.f;
}

// ---------------- main layer kernel ----------------
// Barrier-free: each wave streams its A-fragments from global (L2-resident slab)
// into a 2-deep register pipeline. No main-loop LDS, no __syncthreads anywhere.
// 4 waves/block, 4 batches/block. Wave (half,pair): half = M-split (mt 0-6 / 7-12),
// pair = batch pair. K-order nrun-major; x and h register-resident.
template <int NR>
__global__ __launch_bounds__(256, 2) void k_layer(
    const f16* __restrict__ xg,     // transposed x (= h0 buffer), [2048][32][104]
    const f16* __restrict__ hg,     // hidden input, same layout
    const f16* __restrict__ slabg,  // [NR*10][6656] f16, permuted layout
    const float* __restrict__ biasg,// [208], zero-padded
    f16* __restrict__ houtg,        // next hidden (or nullptr)
    float* __restrict__ outg,       // d_out [2048][400]
    int direct_lo, int outbase) {
    constexpr int NSTEPS = NR * 10;
    // epilogue-only scratch: half-0 waves transpose their pair's 2 hidden batches
    __shared__ __align__(16) f16 scr[2][2 * HBATCH];       // 26624 B

    const int tid = threadIdx.x;
    const int w = tid >> 6;
    const int lane = tid & 63;
    const int pair = w & 1;
    const int half = w >> 1;
    const int b0i = blockIdx.x * 4 + pair * 2;
    const int quad = lane >> 4;
    const int d0 = lane & 15;
    const int mtbase = half * 7;     // 0 or 7
    const int nmt = half ? 6 : 7;

    // preload ALL x scalars this lane ever needs: xr[b][mg] = {d-half0, d-half1}
    const f16* xrow0 = xg + (size_t)(b0i + 0) * HBATCH;
    const f16* xrow1 = xg + (size_t)(b0i + 1) * HBATCH;
    f16x2 xr0[10], xr1[10];          // 20 VGPRs
#pragma unroll
    for (int mg = 0; mg < 10; ++mg) {
        int m = mg * 4 + quad;       // m=39 is the zero pad row
        xr0[mg][0] = xrow0[d0 * HROW + m];
        xr0[mg][1] = xrow0[(d0 + 16) * HROW + m];
        xr1[mg][0] = xrow1[d0 * HROW + m];
        xr1[mg][1] = xrow1[(d0 + 16) * HROW + m];
    }

    // per-lane A source: slab[s][mtbase+mt][lane][0..7]
    const f16* abase = slabg + ((size_t)mtbase * 64 + lane) * 8;

    // 2-deep register pipeline of A fragments
    f16x8 pA0[7], pA1[7];            // 56 VGPRs
#pragma unroll
    for (int mt = 0; mt < 7; ++mt) {
        if (mt < nmt) {
            pA0[mt] = *(const f16x8*)(abase + (size_t)0 * SLAB_F16S + mt * 512);
            pA1[mt] = *(const f16x8*)(abase + (size_t)1 * SLAB_F16S + mt * 512);
        }
    }

    f32x4 acc[7][2][2];              // [mt][d-half][batch] = 112 VGPRs
#pragma unroll
    for (int mt = 0; mt < 7; ++mt)
#pragma unroll
        for (int nt = 0; nt < 2; ++nt)
#pragma unroll
            for (int bb = 0; bb < 2; ++bb)
                acc[mt][nt][bb] = (f32x4)0.f;

    const f16* hrow0 = hg + (size_t)(b0i + 0) * HBATCH;
    const f16* hrow1 = hg + (size_t)(b0i + 1) * HBATCH;

    for (int nr = 0; nr < NR; ++nr) {
        // h fragments for this nrun (register-resident for 10 sub-steps)
        f16x8 h00 = *(const f16x8*)&hrow0[d0 * HROW + nr * 8];
        f16x8 h01 = *(const f16x8*)&hrow0[(d0 + 16) * HROW + nr * 8];
        f16x8 h10 = *(const f16x8*)&hrow1[d0 * HROW + nr * 8];
        f16x8 h11 = *(const f16x8*)&hrow1[(d0 + 16) * HROW + nr * 8];

#pragma unroll
        for (int mg = 0; mg < 10; ++mg) {
            const int s = nr * 10 + mg;     // current sub-step (pA[s&1] == pA[mg&1])

            // B fragments: Z[k][d] = x[d,m]*h[d,n];  k = quad*8+j
            f16x8 b00 = h00 * xr0[mg][0];
            f16x8 b01 = h01 * xr0[mg][1];
            f16x8 b10 = h10 * xr1[mg][0];
            f16x8 b11 = h11 * xr1[mg][1];

#pragma unroll
            for (int mt = 0; mt < 7; ++mt) {
                if (mt < nmt) {
                    f16x8 a = (mg & 1) ? pA1[mt] : pA0[mt];
                    acc[mt][0][0] = __builtin_amdgcn_mfma_f32_16x16x32_f16(a, b00, acc[mt][0][0], 0, 0, 0);
                    acc[mt][1][0] = __builtin_amdgcn_mfma_f32_16x16x32_f16(a, b01, acc[mt][1][0], 0, 0, 0);
                    acc[mt][0][1] = __builtin_amdgcn_mfma_f32_16x16x32_f16(a, b10, acc[mt][0][1], 0, 0, 0);
                    acc[mt][1][1] = __builtin_amdgcn_mfma_f32_16x16x32_f16(a, b11, acc[mt][1][1], 0, 0, 0);
                }
            }

            // refill the buffer just consumed with step s+2
            const int sp = s + 2;
            if (sp < NSTEPS) {
                const f16* src = abase + (size_t)sp * SLAB_F16S;
#pragma unroll
                for (int mt = 0; mt < 7; ++mt) {
                    if (mt < nmt) {
                        f16x8 v = *(const f16x8*)(src + mt * 512);
                        if (mg & 1) pA1[mt] = v; else pA0[mt] = v;
                    }
                }
            }
        }
    }

    // -------- epilogue (wave-independent; no __syncthreads) --------
    const bool wrh = (houtg != nullptr);
    f16* sc = &scr[pair][0];         // this pair's 2-batch scratch (half-0 waves only)
    if (wrh && half == 0) {
        unsigned int* sz = (unsigned int*)sc;
        for (int i = lane; i < HBATCH; i += 64) sz[i] = 0u;   // zero 2*HBATCH f16
    }

#pragma unroll
    for (int mt = 0; mt < 7; ++mt) {
        if (mt < nmt) {
#pragma unroll
            for (int bb = 0; bb < 2; ++bb) {
                float v[2][4];
#pragma unroll
                for (int nt = 0; nt < 2; ++nt)
#pragma unroll
                    for (int i = 0; i < 4; ++i) {
                        int o = (mtbase + mt) * 16 + quad * 4 + i;
                        float t = acc[mt][nt][bb][i] + biasg[o];
                        v[nt][i] = t > 0.f ? t : 0.f;
                    }
                if (wrh && half == 0) {  // hidden rows o<100 all live in half 0
#pragma unroll
                    for (int nt = 0; nt < 2; ++nt)
#pragma unroll
                        for (int i = 0; i < 4; ++i) {
                            int o = mt * 16 + quad * 4 + i;
                            if (o < 100)
                                sc[bb * HBATCH + (d0 + 16 * nt) * HROW + o] = (f16)v[nt][i];
                        }
                }
                float s[4];
#pragma unroll
                for (int i = 0; i < 4; ++i) s[i] = v[0][i] + v[1][i];
#pragma unroll
                for (int mask = 1; mask <= 8; mask <<= 1)
#pragma unroll
                    for (int i = 0; i < 4; ++i) s[i] += __shfl_xor(s[i], mask, 64);
                if (d0 == 0) {
#pragma unroll
                    for (int i = 0; i < 4; ++i) {
                        int o = (mtbase + mt) * 16 + quad * 4 + i;
                        if (o >= direct_lo && o < 200)
                            outg[(size_t)(b0i + bb) * 400 + outbase + (o - direct_lo)] = s[i];
                    }
                }
            }
        }
    }

    if (wrh && half == 0) {
        // copy this pair's 2 transposed hidden batches to global (coalesced u32)
        const unsigned int* s2 = (const unsigned int*)sc;
        unsigned int* dg = (unsigned int*)(houtg + (size_t)b0i * HBATCH);
        for (int i = lane; i < HBATCH; i += 64) dg[i] = s2[i];
    }
}

// ---------------- launch ----------------

extern "C" void kernel_launch(void* const* d_in, const int* in_sizes, int n_in,
                              void* d_out, int out_size, void* d_ws, size_t ws_size,
                              hipStream_t stream) {
    const float* x  = (const float*)d_in[0];
    const float* W0 = (const float*)d_in[1];
    const float* b0 = (const float*)d_in[2];
    const float* W1 = (const float*)d_in[3];
    const float* b1 = (const float*)d_in[4];
    const float* W2 = (const float*)d_in[5];
    const float* b2 = (const float*)d_in[6];
    float* out = (float*)d_out;
    char* ws = (char*)d_ws;

    f16* h0 = (f16*)(ws + OFF_H0);
    f16* h1 = (f16*)(ws + OFF_H1);
    f16* h2 = (f16*)(ws + OFF_H2);
    f16* w0s = (f16*)(ws + OFF_W0);
    f16* w1s = (f16*)(ws + OFF_W1);
    f16* w2s = (f16*)(ws + OFF_W2);
    float* biasws = (float*)(ws + OFF_BIAS);

    {
        long tot = (long)NB_TOT * HBATCH;
        k_prep_h0<<<(unsigned)((tot + 255) / 256), 256, 0, stream>>>(x, h0);
    }
    k_prep_w<<<(unsigned)(((long)50 * SLAB_F16S + 255) / 256), 256, 0, stream>>>(W0, w0s, 50, 39);
    k_prep_w<<<(unsigned)(((long)130 * SLAB_F16S + 255) / 256), 256, 0, stream>>>(W1, w1s, 130, 100);
    k_prep_w<<<(unsigned)(((long)130 * SLAB_F16S + 255) / 256), 256, 0, stream>>>(W2, w2s, 130, 100);
    k_prep_bias<<<3, 256, 0, stream>>>(b0, b1, b2, biasws);

    // layer 0: hidden=x (hn=39, NR=5); direct = cur[100:200] -> out[:,0:100)
    k_layer<5><<<512, 256, 0, stream>>>(h0, h0, w0s, biasws + 0, h1, out, 100, 0);
    // layer 1: hn=100, NR=13; direct = cur[100:200] -> out[:,100:200)
    k_layer<13><<<512, 256, 0, stream>>>(h0, h1, w1s, biasws + 208, h2, out, 100, 100);
    // layer 2: hn=100, NR=13; direct = full cur -> out[:,200:400)
    k_layer<13><<<512, 256, 0, stream>>>(h0, h2, w2s, biasws + 416, (f16*)nullptr, out, 0, 200);
}

// Round 6
// 1846.777 us; speedup vs baseline: 1.8906x; 1.8906x over previous
//
#include <hip/hip_runtime.h>
#include <cstdint>
#include <cstddef>

typedef _Float16 f16;
typedef _Float16 f16x2 __attribute__((ext_vector_type(2)));
typedef _Float16 f16x8 __attribute__((ext_vector_type(8)));
typedef float f32x4 __attribute__((ext_vector_type(4)));

#define NB_TOT   2048
#define F0_      39
#define DDIM     32
#define HROW     104            // padded hidden row (f16), 208B, 16B-aligned rows
#define HBATCH   (DDIM*HROW)    // 3328 f16 per batch
// slab: [step][mt(14)][lane(64)][j(8)] f16, padded to stride 8192 f16 (16384 B)
#define SLAB_F16S 8192
#define SLAB_REAL 7168
#define SLAB_BYTES 16384

// workspace layout (bytes)
#define SZ_H     ((size_t)NB_TOT*HBATCH*2)
#define OFF_H0   ((size_t)0)
#define OFF_H1   (OFF_H0 + SZ_H)
#define OFF_H2   (OFF_H1 + SZ_H)
#define OFF_W0   (OFF_H2 + SZ_H)
#define SZ_W0    ((size_t)50*SLAB_BYTES)
#define OFF_W1   (OFF_W0 + SZ_W0)
#define SZ_W12   ((size_t)130*SLAB_BYTES)
#define OFF_W2   (OFF_W1 + SZ_W12)
#define OFF_BIAS (OFF_W2 + SZ_W12)

// ---------------- prep kernels ----------------

// h0[b][d][n] = (n<39) ? x[b][n][d] : 0   (fp16, transposed, zero-padded)
__global__ void k_prep_h0(const float* __restrict__ x, f16* __restrict__ h0) {
    long idx = (long)blockIdx.x * 256 + threadIdx.x;
    if (idx >= (long)NB_TOT * HBATCH) return;
    int n = (int)(idx % HROW);
    long t = idx / HROW;
    int d = (int)(t % DDIM);
    long b = t / DDIM;
    float v = 0.f;
    if (n < F0_) v = x[(b * F0_ + n) * DDIM + d];
    h0[idx] = (f16)v;
}

// slab[step][mt(14)][lane][j] = W[m*hn+n][o]; stride-padded to 8192 f16/step
//   lane = quad*16+d0; o = mt*16+d0; m = (step%10)*4+quad; n = (step/10)*8+j
// zeros where o>=200 | m>=39 | n>=hn | e>=7168
__global__ void k_prep_w(const float* __restrict__ W, f16* __restrict__ slab,
                         int nsteps, int hn) {
    long idx = (long)blockIdx.x * 256 + threadIdx.x;
    if (idx >= (long)nsteps * SLAB_F16S) return;
    int e = (int)(idx % SLAB_F16S);
    int step = (int)(idx / SLAB_F16S);
    float v = 0.f;
    if (e < SLAB_REAL) {
        int j = e & 7;
        int lane = (e >> 3) & 63;
        int mt = e >> 9;
        int quad = lane >> 4, d0 = lane & 15;
        int o = mt * 16 + d0;
        int m = (step % 10) * 4 + quad;
        int n = (step / 10) * 8 + j;
        if (o < 200 && m < F0_ && n < hn)
            v = W[((long)m * hn + n) * 200 + o];
    }
    slab[idx] = (f16)v;
}

// bias padded to 224 per layer (mt 13 pad tile reads bias[208..223] = 0)
__global__ void k_prep_bias(const float* __restrict__ b0, const float* __restrict__ b1,
                            const float* __restrict__ b2, float* __restrict__ dst) {
    int idx = blockIdx.x * 256 + threadIdx.x;
    if (idx >= 3 * 224) return;
    int L = idx / 224, o = idx % 224;
    const float* s = (L == 0) ? b0 : (L == 1 ? b1 : b2);
    dst[idx] = (o < 200) ? s[o] : 0.f;
}

// ---------------- main layer kernel ----------------

__device__ __forceinline__ void gl_lds16(const void* g, void* l) {
    __builtin_amdgcn_global_load_lds(
        (const __attribute__((address_space(1))) unsigned int*)g,
        (__attribute__((address_space(3))) unsigned int*)l,
        16, 0, 0);
}

// one step-slab = 1024 x 16B chunks; 256 threads x exactly 4 loads (wave-uniform vmcnt)
__device__ __forceinline__ void stage_slab(const f16* __restrict__ g, f16* l, int tid) {
#pragma unroll
    for (int rr = 0; rr < 4; ++rr) {
        int c = rr * 256 + tid;
        gl_lds16((const char*)g + (size_t)c * 16, (char*)l + (size_t)c * 16);
    }
}

// 4 waves/block, 4 batches/block. Wave (half,pair): half = M-split (mt 0-6 / 7-13),
// pair = batch pair. K-order nrun-major; x register-resident; h from global per nr.
// Ring-3 LDS + counted vmcnt: stage(s+2) in flight while computing s; one barrier/step.
template <int NR>
__global__ __launch_bounds__(256, 2) void k_layer(
    const f16* __restrict__ xg,     // transposed x (= h0 buffer), [2048][32][104]
    const f16* __restrict__ hg,     // hidden input, same layout
    const f16* __restrict__ slabg,  // [NR*10][8192] f16, permuted+padded layout
    const float* __restrict__ biasg,// [224], zero-padded
    f16* __restrict__ houtg,        // next hidden (or nullptr)
    float* __restrict__ outg,       // d_out [2048][400]
    int direct_lo, int outbase) {
    constexpr int NSTEPS = NR * 10;
    __shared__ __align__(16) f16 ring[3][SLAB_F16S];   // 49152 B (only LDS)

    const int tid = threadIdx.x;
    const int w = tid >> 6;
    const int lane = tid & 63;
    const int pair = w & 1;
    const int half = w >> 1;
    const int b0i = blockIdx.x * 4 + pair * 2;
    const int quad = lane >> 4;
    const int d0 = lane & 15;
    const int mtbase = half * 7;     // 0 or 7 (mt 13 is the zero pad tile)

    // preload ALL x scalars this lane ever needs: xr[b][mg] = {d-half0, d-half1}
    const f16* xrow0 = xg + (size_t)(b0i + 0) * HBATCH;
    const f16* xrow1 = xg + (size_t)(b0i + 1) * HBATCH;
    f16x2 xr0[10], xr1[10];          // 20 VGPRs
#pragma unroll
    for (int mg = 0; mg < 10; ++mg) {
        int m = mg * 4 + quad;       // m=39 is the zero pad row
        xr0[mg][0] = xrow0[d0 * HROW + m];
        xr0[mg][1] = xrow0[(d0 + 16) * HROW + m];
        xr1[mg][0] = xrow1[d0 * HROW + m];
        xr1[mg][1] = xrow1[(d0 + 16) * HROW + m];
    }

    // prologue staging: steps 0 and 1
    stage_slab(slabg + (size_t)0 * SLAB_F16S, &ring[0][0], tid);
    stage_slab(slabg + (size_t)1 * SLAB_F16S, &ring[1][0], tid);

    f32x4 acc[7][2][2];              // [mt][d-half][batch] -> AGPRs (112)
#pragma unroll
    for (int mt = 0; mt < 7; ++mt)
#pragma unroll
        for (int nt = 0; nt < 2; ++nt)
#pragma unroll
            for (int bb = 0; bb < 2; ++bb)
                acc[mt][nt][bb] = (f32x4)0.f;

    const f16* hrow0 = hg + (size_t)(b0i + 0) * HBATCH;
    const f16* hrow1 = hg + (size_t)(b0i + 1) * HBATCH;

    int bufc = 0;                    // s % 3
    for (int nr = 0; nr < NR; ++nr) {
        // h fragments for this nrun from global (L1/L2-resident; compiler-managed waits)
        f16x8 h00 = *(const f16x8*)&hrow0[d0 * HROW + nr * 8];
        f16x8 h01 = *(const f16x8*)&hrow0[(d0 + 16) * HROW + nr * 8];
        f16x8 h10 = *(const f16x8*)&hrow1[d0 * HROW + nr * 8];
        f16x8 h11 = *(const f16x8*)&hrow1[(d0 + 16) * HROW + nr * 8];
        const bool last_nr = (nr == NR - 1);

#pragma unroll
        for (int mg = 0; mg < 10; ++mg) {
            // --- wait: stage(s) landed (counted; never drain the pipeline) ---
            if (mg == 9 && last_nr) {
                asm volatile("s_waitcnt vmcnt(0)");
            } else {
                asm volatile("s_waitcnt vmcnt(4)");
            }
            __builtin_amdgcn_sched_barrier(0);
            __builtin_amdgcn_s_barrier();
            __builtin_amdgcn_sched_barrier(0);

            // --- stage s+2 into the buffer freed at step s-1 ---
            {
                int sp = nr * 10 + mg + 2;
                if (sp < NSTEPS) {
                    int dst = bufc + 2; if (dst >= 3) dst -= 3;
                    stage_slab(slabg + (size_t)sp * SLAB_F16S, &ring[dst][0], tid);
                }
            }

            // B fragments: Z[k][d] = x[d,m]*h[d,n];  k = quad*8+j
            f16x8 b00 = h00 * xr0[mg][0];
            f16x8 b01 = h01 * xr0[mg][1];
            f16x8 b10 = h10 * xr1[mg][0];
            f16x8 b11 = h11 * xr1[mg][1];

            const f16* abase = &ring[bufc][(size_t)mtbase * 512 + lane * 8];
            __builtin_amdgcn_s_setprio(1);
#pragma unroll
            for (int mt = 0; mt < 7; ++mt) {
                f16x8 a = *(const f16x8*)(abase + mt * 512);
                acc[mt][0][0] = __builtin_amdgcn_mfma_f32_16x16x32_f16(a, b00, acc[mt][0][0], 0, 0, 0);
                acc[mt][1][0] = __builtin_amdgcn_mfma_f32_16x16x32_f16(a, b01, acc[mt][1][0], 0, 0, 0);
                acc[mt][0][1] = __builtin_amdgcn_mfma_f32_16x16x32_f16(a, b10, acc[mt][0][1], 0, 0, 0);
                acc[mt][1][1] = __builtin_amdgcn_mfma_f32_16x16x32_f16(a, b11, acc[mt][1][1], 0, 0, 0);
            }
            __builtin_amdgcn_s_setprio(0);

            bufc = bufc + 1; if (bufc >= 3) bufc = 0;
        }
    }

    // -------- epilogue --------
    __syncthreads();   // full drain once; ring becomes scratch

    const bool wrh = (houtg != nullptr);
    f16* sc = ((f16*)ring) + (size_t)pair * (2 * HBATCH);   // 2 pairs x 13312 B <= 49152 B
    if (wrh && half == 0) {
        unsigned int* sz = (unsigned int*)sc;
        for (int i = lane; i < HBATCH; i += 64) sz[i] = 0u;   // zero 2*HBATCH f16
    }

#pragma unroll
    for (int mt = 0; mt < 7; ++mt) {
#pragma unroll
        for (int bb = 0; bb < 2; ++bb) {
            float v[2][4];
#pragma unroll
            for (int nt = 0; nt < 2; ++nt)
#pragma unroll
                for (int i = 0; i < 4; ++i) {
                    int o = (mtbase + mt) * 16 + quad * 4 + i;
                    float t = acc[mt][nt][bb][i] + biasg[o];
                    v[nt][i] = t > 0.f ? t : 0.f;
                }
            if (wrh && half == 0) {  // hidden rows o<100 all live in half 0
#pragma unroll
                for (int nt = 0; nt < 2; ++nt)
#pragma unroll
                    for (int i = 0; i < 4; ++i) {
                        int o = mt * 16 + quad * 4 + i;
                        if (o < 100)
                            sc[bb * HBATCH + (d0 + 16 * nt) * HROW + o] = (f16)v[nt][i];
                    }
            }
            float s[4];
#pragma unroll
            for (int i = 0; i < 4; ++i) s[i] = v[0][i] + v[1][i];
#pragma unroll
            for (int mask = 1; mask <= 8; mask <<= 1)
#pragma unroll
                for (int i = 0; i < 4; ++i) s[i] += __shfl_xor(s[i], mask, 64);
            if (d0 == 0) {
#pragma unroll
                for (int i = 0; i < 4; ++i) {
                    int o = (mtbase + mt) * 16 + quad * 4 + i;
                    if (o >= direct_lo && o < 200)
                        outg[(size_t)(b0i + bb) * 400 + outbase + (o - direct_lo)] = s[i];
                }
            }
        }
    }

    if (wrh && half == 0) {
        // copy this pair's 2 transposed hidden batches to global (coalesced u32)
        const unsigned int* s2 = (const unsigned int*)sc;
        unsigned int* dg = (unsigned int*)(houtg + (size_t)b0i * HBATCH);
        for (int i = lane; i < HBATCH; i += 64) dg[i] = s2[i];
    }
}

// ---------------- launch ----------------

extern "C" void kernel_launch(void* const* d_in, const int* in_sizes, int n_in,
                              void* d_out, int out_size, void* d_ws, size_t ws_size,
                              hipStream_t stream) {
    const float* x  = (const float*)d_in[0];
    const float* W0 = (const float*)d_in[1];
    const float* b0 = (const float*)d_in[2];
    const float* W1 = (const float*)d_in[3];
    const float* b1 = (const float*)d_in[4];
    const float* W2 = (const float*)d_in[5];
    const float* b2 = (const float*)d_in[6];
    float* out = (float*)d_out;
    char* ws = (char*)d_ws;

    f16* h0 = (f16*)(ws + OFF_H0);
    f16* h1 = (f16*)(ws + OFF_H1);
    f16* h2 = (f16*)(ws + OFF_H2);
    f16* w0s = (f16*)(ws + OFF_W0);
    f16* w1s = (f16*)(ws + OFF_W1);
    f16* w2s = (f16*)(ws + OFF_W2);
    float* biasws = (float*)(ws + OFF_BIAS);

    {
        long tot = (long)NB_TOT * HBATCH;
        k_prep_h0<<<(unsigned)((tot + 255) / 256), 256, 0, stream>>>(x, h0);
    }
    k_prep_w<<<(unsigned)(((long)50 * SLAB_F16S + 255) / 256), 256, 0, stream>>>(W0, w0s, 50, 39);
    k_prep_w<<<(unsigned)(((long)130 * SLAB_F16S + 255) / 256), 256, 0, stream>>>(W1, w1s, 130, 100);
    k_prep_w<<<(unsigned)(((long)130 * SLAB_F16S + 255) / 256), 256, 0, stream>>>(W2, w2s, 130, 100);
    k_prep_bias<<<3, 256, 0, stream>>>(b0, b1, b2, biasws);

    // layer 0: hidden=x (hn=39, NR=5); direct = cur[100:200] -> out[:,0:100)
    k_layer<5><<<512, 256, 0, stream>>>(h0, h0, w0s, biasws + 0, h1, out, 100, 0);
    // layer 1: hn=100, NR=13; direct = cur[100:200] -> out[:,100:200)
    k_layer<13><<<512, 256, 0, stream>>>(h0, h1, w1s, biasws + 224, h2, out, 100, 100);
    // layer 2: hn=100, NR=13; direct = full cur -> out[:,200:400)
    k_layer<13><<<512, 256, 0, stream>>>(h0, h2, w2s, biasws + 448, (f16*)nullptr, out, 0, 200);
}